// Round 9
// baseline (346.234 us; speedup 1.0000x reference)
//
#include <hip/hip_runtime.h>
#include <hip/hip_bf16.h>

typedef __bf16 bf16x8 __attribute__((ext_vector_type(8)));
typedef float floatx4 __attribute__((ext_vector_type(4)));

#define LDW 136  // activation row stride
#define PXW 40   // pre_msg row stride (cols 0..2 recv-x, 3..5 self-x, rest pad)

// ws layout (bf16 element offsets). Big mats: Wt[n][k]. K32 pads: [128 n][32 k].
// N16 tails: [16 n][128 k].
#define O_E1W2  0
#define O_E2W1  16384
#define O_E2W2  49152
#define O_E3W1  65536
#define O_E3W2  81920
#define O_E4W1  98304
#define O_E4W2  131072
#define O_DM2T0 147456
#define O_DM2T1 163840
#define O_DO1   180224
#define O_DO2   196608
#define O_EWOUT 212992
#define O_DW3   215040
#define O_E1W1P 217088
#define O_M1T0P 221184
#define O_M1T1P 225280
#define O_DO1XP 229376
#define WS_ELEMS 233472

__global__ void prep_kernel(const float* e1w2, const float* e2w1, const float* e2w2,
    const float* e3w1, const float* e3w2, const float* e4w1, const float* e4w2,
    const float* dmsg2, const float* dout1, const float* dout2,
    const float* ew_out, const float* dout_w3, const float* e1w1,
    const float* dmsg_w1, __hip_bfloat16* ws) {
  int idx = blockIdx.x * 256 + threadIdx.x;
  if (idx >= WS_ELEMS) return;
  float v;
  if (idx < O_E2W1)      { int l = idx;           v = e1w2[(l & 127) * 128 + (l >> 7)]; }
  else if (idx < O_E2W2) { int l = idx - O_E2W1;  v = e2w1[(l & 255) * 128 + (l >> 8)]; }
  else if (idx < O_E3W1) { int l = idx - O_E2W2;  v = e2w2[(l & 127) * 128 + (l >> 7)]; }
  else if (idx < O_E3W2) { int l = idx - O_E3W1;  v = e3w1[(l & 127) * 128 + (l >> 7)]; }
  else if (idx < O_E4W1) { int l = idx - O_E3W2;  v = e3w2[(l & 127) * 128 + (l >> 7)]; }
  else if (idx < O_E4W2) { int l = idx - O_E4W1;  v = e4w1[(l & 255) * 128 + (l >> 8)]; }
  else if (idx < O_DM2T0){ int l = idx - O_E4W2;  v = e4w2[(l & 127) * 128 + (l >> 7)]; }
  else if (idx < O_DM2T1){ int l = idx - O_DM2T0; v = dmsg2[(l & 127) * 128 + (l >> 7)]; }
  else if (idx < O_DO1)  { int l = idx - O_DM2T1; v = dmsg2[16384 + (l & 127) * 128 + (l >> 7)]; }
  else if (idx < O_DO2)  { int l = idx - O_DO1;   v = dout1[384 + (l & 127) * 128 + (l >> 7)]; }
  else if (idx < O_EWOUT){ int l = idx - O_DO2;   v = dout2[(l & 127) * 128 + (l >> 7)]; }
  else if (idx < O_DW3)  { int l = idx - O_EWOUT; int n = l >> 7;
                           v = (n < 2) ? ew_out[(l & 127) * 2 + n] : 0.f; }
  else if (idx < O_E1W1P){ int l = idx - O_DW3;   int n = l >> 7;
                           v = (n < 3) ? dout_w3[(l & 127) * 3 + n] : 0.f; }
  else if (idx < O_M1T0P){ int l = idx - O_E1W1P; int n = l >> 5, c = l & 31;
                           v = (c >= 3 && c < 6) ? e1w1[(c - 3) * 128 + n] : 0.f; }
  else if (idx < O_M1T1P){ int l = idx - O_M1T0P; int n = l >> 5, c = l & 31;
                           v = (c < 6) ? dmsg_w1[c * 128 + n] : 0.f; }
  else if (idx < O_DO1XP){ int l = idx - O_M1T1P; int n = l >> 5, c = l & 31;
                           v = (c < 6) ? dmsg_w1[768 + c * 128 + n] : 0.f; }
  else                   { int l = idx - O_DO1XP; int n = l >> 5, c = l & 31;
                           v = (c >= 3 && c < 6) ? dout1[(c - 3) * 128 + n] : 0.f; }
  ws[idx] = __float2bfloat16(v);
}

// 16 graphs/WG (96 rows), 512 threads = 8 waves tiled 2D:
// rowgroup = wave>>2 (48 rows, graph-aligned), colgroup = wave&3 (32 cols).
// Halves per-stage LDS act-read traffic vs R8 (each wave reads 12KB not 24KB).
__global__ __launch_bounds__(512, 4) void nri_fused(
    const float* __restrict__ x,
    const float* __restrict__ e1b1, const float* __restrict__ e1b2,
    const float* __restrict__ e2b1, const float* __restrict__ e2b2,
    const float* __restrict__ e3b1, const float* __restrict__ e3b2,
    const float* __restrict__ e4b1, const float* __restrict__ e4b2,
    const float* __restrict__ eb_out,
    const float* __restrict__ dmsg_b1, const float* __restrict__ dmsg_b2,
    const float* __restrict__ dout_b1, const float* __restrict__ dout_b2,
    const float* __restrict__ dout_b3,
    const __bf16* __restrict__ wt, float* __restrict__ out)
{
  const int tid  = threadIdx.x;
  const int wave = tid >> 6;
  const int lane = tid & 63;
  const int nl   = lane & 15;
  const int quad = lane >> 4;
  const int rb   = (wave >> 2) * 48;       // row-group base (graph-aligned)
  const int cb   = (wave & 3) * 32;        // col-group base
  const int gx   = blockIdx.x * 288;

  __shared__ __align__(16) __hip_bfloat16 bufA[96 * LDW];
  __shared__ __align__(16) __hip_bfloat16 bufB[96 * LDW];
  __shared__ __align__(16) __hip_bfloat16 pxb[96 * PXW];
  __shared__ __align__(16) float biasL[16 * 128];
  __shared__ float rtw[192];
  __shared__ float xs[288];
  __shared__ float obuf[288];

  // ---- stage 0: stage x, bias table, pre_msg (all grid-stride: R6 lesson) ----
  for (int i = tid; i < 288; i += 512) xs[i] = x[gx + i];
  for (int i = tid; i < 2048; i += 512) {
    int row = i >> 7, c = i & 127;
    float v;
    switch (row) {
      case 0: v = e1b1[c]; break;   case 1: v = e1b2[c]; break;
      case 2: v = e2b1[c]; break;   case 3: v = e2b2[c]; break;
      case 4: v = e3b1[c]; break;   case 5: v = e3b2[c]; break;
      case 6: v = e4b1[c]; break;   case 7: v = e4b2[c]; break;
      case 8: v = dmsg_b1[c]; break;  case 9: v = dmsg_b1[128 + c]; break;
      case 10: v = dmsg_b2[c]; break; case 11: v = dmsg_b2[128 + c]; break;
      case 12: v = dout_b1[c]; break; case 13: v = dout_b2[c]; break;
      case 14: v = (c < 2) ? eb_out[c] : 0.f; break;
      default: v = (c < 3) ? dout_b3[c] : 0.f; break;
    }
    biasL[i] = v;
  }
  for (int i = tid; i < 96 * 32; i += 512) {
    int row = i >> 5, c = i & 31;
    int e = row % 6;
    float v = 0.f;
    if (c < 3)      { int rr = row + ((e == 5) ? -5 : 1); v = x[gx + rr * 3 + c]; }
    else if (c < 6) v = x[gx + row * 3 + (c - 3)];
    pxb[row * PXW + c] = __float2bfloat16(v);
  }
  __syncthreads();

  auto initb = [&](floatx4 (&a)[3][2], int brow) {
#pragma unroll
    for (int nt = 0; nt < 2; ++nt) {
      float bv = biasL[brow * 128 + cb + nt * 16 + nl];
      floatx4 v = {bv, bv, bv, bv};
#pragma unroll
      for (int mt = 0; mt < 3; ++mt) a[mt][nt] = v;
    }
  };

  auto gemm128 = [&](floatx4 (&acc)[3][2], const __hip_bfloat16* in, const __bf16* w) {
    const __bf16* ab = (const __bf16*)(const void*)in;
    const __bf16* w0 = w + (cb + nl) * 128 + quad * 8;
    const __bf16* w1 = w0 + 16 * 128;
#pragma unroll
    for (int ks = 0; ks < 4; ++ks) {
      int kk = ks * 32 + quad * 8;
      bf16x8 b0 = *(const bf16x8*)(w0 + ks * 32);
      bf16x8 b1 = *(const bf16x8*)(w1 + ks * 32);
#pragma unroll
      for (int mt = 0; mt < 3; ++mt) {
        bf16x8 a = *(const bf16x8*)(ab + (rb + mt * 16 + nl) * LDW + kk);
        acc[mt][0] = __builtin_amdgcn_mfma_f32_16x16x32_bf16(a, b0, acc[mt][0], 0, 0, 0);
        acc[mt][1] = __builtin_amdgcn_mfma_f32_16x16x32_bf16(a, b1, acc[mt][1], 0, 0, 0);
      }
    }
  };

  auto gemm256 = [&](floatx4 (&acc)[3][2], const __hip_bfloat16* in0, bool recv0,
                     const __hip_bfloat16* in1, const __bf16* w) {
    int rofs0[3], rofs1[3];
#pragma unroll
    for (int mt = 0; mt < 3; ++mt) {
      int r = rb + mt * 16 + nl;
      rofs1[mt] = r * LDW;
      if (recv0) { int e = r % 6; r += (e == 5) ? -5 : 1; }
      rofs0[mt] = r * LDW;
    }
    const __bf16* ab0 = (const __bf16*)(const void*)in0;
    const __bf16* ab1 = (const __bf16*)(const void*)in1;
    const __bf16* w0 = w + (cb + nl) * 256 + quad * 8;
    const __bf16* w1 = w0 + 16 * 256;
#pragma unroll
    for (int ks = 0; ks < 8; ++ks) {
      int kk = (ks & 3) * 32 + quad * 8;
      const __bf16* ab = (ks < 4) ? ab0 : ab1;
      const int* rofs = (ks < 4) ? rofs0 : rofs1;
      bf16x8 b0 = *(const bf16x8*)(w0 + ks * 32);
      bf16x8 b1 = *(const bf16x8*)(w1 + ks * 32);
#pragma unroll
      for (int mt = 0; mt < 3; ++mt) {
        bf16x8 a = *(const bf16x8*)(ab + rofs[mt] + kk);
        acc[mt][0] = __builtin_amdgcn_mfma_f32_16x16x32_bf16(a, b0, acc[mt][0], 0, 0, 0);
        acc[mt][1] = __builtin_amdgcn_mfma_f32_16x16x32_bf16(a, b1, acc[mt][1], 0, 0, 0);
      }
    }
  };

  // K=32 GEMM: A from pxb, B from padded weight [128][32]
  auto gemm32 = [&](floatx4 (&acc)[3][2], int wofs) {
    const __bf16* pb = (const __bf16*)(const void*)pxb;
    const __bf16* wp = wt + wofs + (cb + nl) * 32 + quad * 8;
    bf16x8 b0 = *(const bf16x8*)(wp);
    bf16x8 b1 = *(const bf16x8*)(wp + 512);
#pragma unroll
    for (int mt = 0; mt < 3; ++mt) {
      bf16x8 a = *(const bf16x8*)(pb + (rb + mt * 16 + nl) * PXW + quad * 8);
      acc[mt][0] = __builtin_amdgcn_mfma_f32_16x16x32_bf16(a, b0, acc[mt][0], 0, 0, 0);
      acc[mt][1] = __builtin_amdgcn_mfma_f32_16x16x32_bf16(a, b1, acc[mt][1], 0, 0, 0);
    }
  };

  // act: 1=ELU 2=ReLU (bias already in acc)
  auto store_act = [&](floatx4 (&acc)[3][2], int act, __hip_bfloat16* ob) {
#pragma unroll
    for (int nt = 0; nt < 2; ++nt) {
      int col = cb + nt * 16 + nl;
#pragma unroll
      for (int mt = 0; mt < 3; ++mt)
#pragma unroll
        for (int r = 0; r < 4; ++r) {
          float z = acc[mt][nt][r];
          if (act == 1) z = (z > 0.f) ? z : (__expf(z) - 1.f);
          else z = fmaxf(z, 0.f);
          ob[(rb + mt * 16 + quad * 4 + r) * LDW + col] = __float2bfloat16(z);
        }
    }
  };

  floatx4 acc[3][2];

  // s1: hh = ELU(x @ e1w1 + b) via K=32 MFMA
  initb(acc, 0); gemm32(acc, O_E1W1P); store_act(acc, 1, bufA);
  __syncthreads();
  // s2: h = ELU(. @ e1w2 + b)
  initb(acc, 1); gemm128(acc, bufA, wt + O_E1W2); store_act(acc, 1, bufB);
  __syncthreads();
  // s3: ELU([h_recv|h] @ e2w1 + b)
  initb(acc, 2); gemm256(acc, bufB, true, bufB, wt + O_E2W1); store_act(acc, 1, bufA);
  __syncthreads();
  // s4: he = ELU(. @ e2w2 + b) -> bufB (keep)
  initb(acc, 3); gemm128(acc, bufA, wt + O_E2W2); store_act(acc, 1, bufB);
  __syncthreads();
  // s5: ELU(he @ e3w1 + b) -> bufA
  initb(acc, 4); gemm128(acc, bufB, wt + O_E3W1); store_act(acc, 1, bufA);
  __syncthreads();
  // s6: h2 = ELU(. @ e3w2 + b) -> bufA in-place
  initb(acc, 5); gemm128(acc, bufA, wt + O_E3W2);
  __syncthreads();
  store_act(acc, 1, bufA);
  __syncthreads();
  // s7: ELU([h2|he] @ e4w1 + b) -> bufA in-place
  initb(acc, 6); gemm256(acc, bufA, false, bufB, wt + O_E4W1);
  __syncthreads();
  store_act(acc, 1, bufA);
  __syncthreads();
  // s8: h3 = ELU(. @ e4w2 + b) -> bufB
  initb(acc, 7); gemm128(acc, bufA, wt + O_E4W2); store_act(acc, 1, bufB);
  __syncthreads();

  // s9: logits via N=16-padded MFMA tail (waves 0..5, one row-tile each)
  if (wave < 6) {
    int tile = wave;
    float bv = biasL[14 * 128 + nl];
    floatx4 lg = {bv, bv, bv, bv};
    const __bf16* ab = (const __bf16*)(const void*)bufB;
    const __bf16* wp = wt + O_EWOUT + nl * 128 + quad * 8;
#pragma unroll
    for (int ks = 0; ks < 4; ++ks) {
      bf16x8 a = *(const bf16x8*)(ab + (tile * 16 + nl) * LDW + ks * 32 + quad * 8);
      bf16x8 b = *(const bf16x8*)(wp + ks * 32);
      lg = __builtin_amdgcn_mfma_f32_16x16x32_bf16(a, b, lg, 0, 0, 0);
    }
    if (nl < 2) {
#pragma unroll
      for (int r = 0; r < 4; ++r)
        rtw[(tile * 16 + quad * 4 + r) * 2 + nl] = lg[r];
    }
  }
  __syncthreads();

  // s10: softmax (tid<96) + m1 both types via K=32 MFMA: t0->bufA, t1->bufB
  if (tid < 96) {
    float l0 = rtw[tid * 2], l1 = rtw[tid * 2 + 1];
    float mx = fmaxf(l0, l1);
    float ea = __expf(l0 - mx), eb = __expf(l1 - mx);
    float inv = 1.f / (ea + eb);
    rtw[tid * 2] = ea * inv; rtw[tid * 2 + 1] = eb * inv;
  }
  {
    floatx4 acc1[3][2];
    initb(acc, 8);  gemm32(acc, O_M1T0P);  store_act(acc, 2, bufA);
    initb(acc1, 9); gemm32(acc1, O_M1T1P); store_act(acc1, 2, bufB);
    __syncthreads();

    // s11: msg = rt0*relu(dm2t0 . m1t0) + rt1*relu(dm2t1 . m1t1)
    initb(acc, 10);  gemm128(acc, bufA, wt + O_DM2T0);
    initb(acc1, 11); gemm128(acc1, bufB, wt + O_DM2T1);
#pragma unroll
    for (int mt = 0; mt < 3; ++mt)
#pragma unroll
      for (int r = 0; r < 4; ++r) {
        int row = rb + mt * 16 + quad * 4 + r;
        float r0 = rtw[row * 2], r1 = rtw[row * 2 + 1];
#pragma unroll
        for (int nt = 0; nt < 2; ++nt)
          acc[mt][nt][r] = r0 * fmaxf(acc[mt][nt][r], 0.f)
                         + r1 * fmaxf(acc1[mt][nt][r], 0.f);
      }
  }
  __syncthreads();

  // s12: agg (edge e -> node (e+1)%6) -> bufA (remap stays inside row-group)
#pragma unroll
  for (int nt = 0; nt < 2; ++nt) {
    int col = cb + nt * 16 + nl;
#pragma unroll
    for (int mt = 0; mt < 3; ++mt)
#pragma unroll
      for (int r = 0; r < 4; ++r) {
        int row = rb + mt * 16 + quad * 4 + r;
        int e = row % 6;
        int orow = row + ((e == 5) ? -5 : 1);
        bufA[orow * LDW + col] = __float2bfloat16(acc[mt][nt][r]);
      }
  }
  __syncthreads();

  // s13: p1 = relu([x|agg] @ d_out_w1 + b) -> bufB  (K=128 MFMA + K=32 MFMA)
  initb(acc, 12); gemm128(acc, bufA, wt + O_DO1); gemm32(acc, O_DO1XP);
  store_act(acc, 2, bufB);
  __syncthreads();
  // s14: p2 = relu(. @ d_out_w2 + b) -> bufA
  initb(acc, 13); gemm128(acc, bufB, wt + O_DO2); store_act(acc, 2, bufA);
  __syncthreads();

  // s15: out = x + p2 @ d_out_w3 + b3 via N=16-padded MFMA tail (waves 0..5)
  if (wave < 6) {
    int tile = wave;
    float bv = biasL[15 * 128 + nl];
    floatx4 d = {bv, bv, bv, bv};
    const __bf16* ab = (const __bf16*)(const void*)bufA;
    const __bf16* wp = wt + O_DW3 + nl * 128 + quad * 8;
#pragma unroll
    for (int ks = 0; ks < 4; ++ks) {
      bf16x8 a = *(const bf16x8*)(ab + (tile * 16 + nl) * LDW + ks * 32 + quad * 8);
      bf16x8 b = *(const bf16x8*)(wp + ks * 32);
      d = __builtin_amdgcn_mfma_f32_16x16x32_bf16(a, b, d, 0, 0, 0);
    }
    if (nl < 3) {
#pragma unroll
      for (int r = 0; r < 4; ++r) {
        int row = tile * 16 + quad * 4 + r;
        obuf[row * 3 + nl] = xs[row * 3 + nl] + d[r];
      }
    }
  }
  __syncthreads();
  for (int i = tid; i < 288; i += 512) out[gx + i] = obuf[i];
}

extern "C" void kernel_launch(void* const* d_in, const int* in_sizes, int n_in,
                              void* d_out, int out_size, void* d_ws, size_t ws_size,
                              hipStream_t stream) {
  const float* x       = (const float*)d_in[0];
  const float* e1w1    = (const float*)d_in[3];
  const float* e1b1    = (const float*)d_in[4];
  const float* e1w2    = (const float*)d_in[5];
  const float* e1b2    = (const float*)d_in[6];
  const float* e2w1    = (const float*)d_in[7];
  const float* e2b1    = (const float*)d_in[8];
  const float* e2w2    = (const float*)d_in[9];
  const float* e2b2    = (const float*)d_in[10];
  const float* e3w1    = (const float*)d_in[11];
  const float* e3b1    = (const float*)d_in[12];
  const float* e3w2    = (const float*)d_in[13];
  const float* e3b2    = (const float*)d_in[14];
  const float* e4w1    = (const float*)d_in[15];
  const float* e4b1    = (const float*)d_in[16];
  const float* e4w2    = (const float*)d_in[17];
  const float* e4b2    = (const float*)d_in[18];
  const float* ew_out  = (const float*)d_in[19];
  const float* eb_out  = (const float*)d_in[20];
  const float* dmsg_w1 = (const float*)d_in[21];
  const float* dmsg_b1 = (const float*)d_in[22];
  const float* dmsg_w2 = (const float*)d_in[23];
  const float* dmsg_b2 = (const float*)d_in[24];
  const float* dout_w1 = (const float*)d_in[25];
  const float* dout_b1 = (const float*)d_in[26];
  const float* dout_w2 = (const float*)d_in[27];
  const float* dout_b2 = (const float*)d_in[28];
  const float* dout_w3 = (const float*)d_in[29];
  const float* dout_b3 = (const float*)d_in[30];

  prep_kernel<<<(WS_ELEMS + 255) / 256, 256, 0, stream>>>(
      e1w2, e2w1, e2w2, e3w1, e3w2, e4w1, e4w2, dmsg_w2, dout_w1, dout_w2,
      ew_out, dout_w3, e1w1, dmsg_w1, (__hip_bfloat16*)d_ws);

  nri_fused<<<32768 / 16, 512, 0, stream>>>(
      x, e1b1, e1b2, e2b1, e2b2, e3b1, e3b2, e4b1, e4b2, eb_out,
      dmsg_b1, dmsg_b2, dout_b1, dout_b2, dout_b3,
      (const __bf16*)d_ws, (float*)d_out);
}

// Round 10
// 267.118 us; speedup vs baseline: 1.2962x; 1.2962x over previous
//
#include <hip/hip_runtime.h>
#include <hip/hip_bf16.h>

typedef __bf16 bf16x8 __attribute__((ext_vector_type(8)));
typedef float floatx4 __attribute__((ext_vector_type(4)));

#define LDW 136  // activation row stride
#define PXW 40   // pre_msg row stride (cols 0..2 recv-x, 3..5 self-x, rest pad)

// ws layout (bf16 element offsets). Big mats: Wt[n][k]. K32 pads: [128 n][32 k].
// N16 tails: [16 n][128 k].
#define O_E1W2  0
#define O_E2W1  16384
#define O_E2W2  49152
#define O_E3W1  65536
#define O_E3W2  81920
#define O_E4W1  98304
#define O_E4W2  131072
#define O_DM2T0 147456
#define O_DM2T1 163840
#define O_DO1   180224
#define O_DO2   196608
#define O_EWOUT 212992
#define O_DW3   215040
#define O_E1W1P 217088
#define O_M1T0P 221184
#define O_M1T1P 225280
#define O_DO1XP 229376
#define WS_ELEMS 233472

__global__ void prep_kernel(const float* e1w2, const float* e2w1, const float* e2w2,
    const float* e3w1, const float* e3w2, const float* e4w1, const float* e4w2,
    const float* dmsg2, const float* dout1, const float* dout2,
    const float* ew_out, const float* dout_w3, const float* e1w1,
    const float* dmsg_w1, __hip_bfloat16* ws) {
  int idx = blockIdx.x * 256 + threadIdx.x;
  if (idx >= WS_ELEMS) return;
  float v;
  if (idx < O_E2W1)      { int l = idx;           v = e1w2[(l & 127) * 128 + (l >> 7)]; }
  else if (idx < O_E2W2) { int l = idx - O_E2W1;  v = e2w1[(l & 255) * 128 + (l >> 8)]; }
  else if (idx < O_E3W1) { int l = idx - O_E2W2;  v = e2w2[(l & 127) * 128 + (l >> 7)]; }
  else if (idx < O_E3W2) { int l = idx - O_E3W1;  v = e3w1[(l & 127) * 128 + (l >> 7)]; }
  else if (idx < O_E4W1) { int l = idx - O_E3W2;  v = e3w2[(l & 127) * 128 + (l >> 7)]; }
  else if (idx < O_E4W2) { int l = idx - O_E4W1;  v = e4w1[(l & 255) * 128 + (l >> 8)]; }
  else if (idx < O_DM2T0){ int l = idx - O_E4W2;  v = e4w2[(l & 127) * 128 + (l >> 7)]; }
  else if (idx < O_DM2T1){ int l = idx - O_DM2T0; v = dmsg2[(l & 127) * 128 + (l >> 7)]; }
  else if (idx < O_DO1)  { int l = idx - O_DM2T1; v = dmsg2[16384 + (l & 127) * 128 + (l >> 7)]; }
  else if (idx < O_DO2)  { int l = idx - O_DO1;   v = dout1[384 + (l & 127) * 128 + (l >> 7)]; }
  else if (idx < O_EWOUT){ int l = idx - O_DO2;   v = dout2[(l & 127) * 128 + (l >> 7)]; }
  else if (idx < O_DW3)  { int l = idx - O_EWOUT; int n = l >> 7;
                           v = (n < 2) ? ew_out[(l & 127) * 2 + n] : 0.f; }
  else if (idx < O_E1W1P){ int l = idx - O_DW3;   int n = l >> 7;
                           v = (n < 3) ? dout_w3[(l & 127) * 3 + n] : 0.f; }
  else if (idx < O_M1T0P){ int l = idx - O_E1W1P; int n = l >> 5, c = l & 31;
                           v = (c >= 3 && c < 6) ? e1w1[(c - 3) * 128 + n] : 0.f; }
  else if (idx < O_M1T1P){ int l = idx - O_M1T0P; int n = l >> 5, c = l & 31;
                           v = (c < 6) ? dmsg_w1[c * 128 + n] : 0.f; }
  else if (idx < O_DO1XP){ int l = idx - O_M1T1P; int n = l >> 5, c = l & 31;
                           v = (c < 6) ? dmsg_w1[768 + c * 128 + n] : 0.f; }
  else                   { int l = idx - O_DO1XP; int n = l >> 5, c = l & 31;
                           v = (c >= 3 && c < 6) ? dout1[(c - 3) * 128 + n] : 0.f; }
  ws[idx] = __float2bfloat16(v);
}

struct W4 { bf16x8 b[4]; };
struct W8 { bf16x8 b[8]; };

// R8 geometry (best: 189us): 16 graphs/WG, 512 thr = 8 waves, wave owns 16 cols.
// R10: + weight prefetch one stage ahead (hide L2 on critical path)
//      + e4w1 split (acc2 = he@e4w1[128:] in s5) removing 2 in-place barriers.
__global__ __launch_bounds__(512, 4) void nri_fused(
    const float* __restrict__ x,
    const float* __restrict__ e1b1, const float* __restrict__ e1b2,
    const float* __restrict__ e2b1, const float* __restrict__ e2b2,
    const float* __restrict__ e3b1, const float* __restrict__ e3b2,
    const float* __restrict__ e4b1, const float* __restrict__ e4b2,
    const float* __restrict__ eb_out,
    const float* __restrict__ dmsg_b1, const float* __restrict__ dmsg_b2,
    const float* __restrict__ dout_b1, const float* __restrict__ dout_b2,
    const float* __restrict__ dout_b3,
    const __bf16* __restrict__ wt, float* __restrict__ out)
{
  const int tid  = threadIdx.x;
  const int wave = tid >> 6;
  const int lane = tid & 63;
  const int nl   = lane & 15;
  const int quad = lane >> 4;
  const int colb = wave * 16 + nl;  // this wave's output column
  const int gx   = blockIdx.x * 288;

  __shared__ __align__(16) __hip_bfloat16 bufA[96 * LDW];
  __shared__ __align__(16) __hip_bfloat16 bufB[96 * LDW];
  __shared__ __align__(16) __hip_bfloat16 pxb[96 * PXW];
  __shared__ __align__(16) float biasL[16 * 128];
  __shared__ float rtw[192];
  __shared__ float xs[288];
  __shared__ float obuf[288];

  // ---- stage 0 (grid-stride everywhere: R6 lesson) ----
  for (int i = tid; i < 288; i += 512) xs[i] = x[gx + i];
  for (int i = tid; i < 2048; i += 512) {
    int row = i >> 7, c = i & 127;
    float v;
    switch (row) {
      case 0: v = e1b1[c]; break;   case 1: v = e1b2[c]; break;
      case 2: v = e2b1[c]; break;   case 3: v = e2b2[c]; break;
      case 4: v = e3b1[c]; break;   case 5: v = e3b2[c]; break;
      case 6: v = e4b1[c]; break;   case 7: v = e4b2[c]; break;
      case 8: v = dmsg_b1[c]; break;  case 9: v = dmsg_b1[128 + c]; break;
      case 10: v = dmsg_b2[c]; break; case 11: v = dmsg_b2[128 + c]; break;
      case 12: v = dout_b1[c]; break; case 13: v = dout_b2[c]; break;
      case 14: v = (c < 2) ? eb_out[c] : 0.f; break;
      default: v = (c < 3) ? dout_b3[c] : 0.f; break;
    }
    biasL[i] = v;
  }
  for (int i = tid; i < 96 * 32; i += 512) {
    int row = i >> 5, c = i & 31;
    int e = row % 6;
    float v = 0.f;
    if (c < 3)      { int rr = row + ((e == 5) ? -5 : 1); v = x[gx + rr * 3 + c]; }
    else if (c < 6) v = x[gx + row * 3 + (c - 3)];
    pxb[row * PXW + c] = __float2bfloat16(v);
  }
  __syncthreads();

  auto initb = [&](floatx4 (&a)[6], int brow) {
    float bv = biasL[brow * 128 + colb];
    floatx4 v = {bv, bv, bv, bv};
#pragma unroll
    for (int mt = 0; mt < 6; ++mt) a[mt] = v;
  };

  // weight fragment prefetch (pure global loads, no LDS dependency)
  auto loadW128 = [&](int wofs) {
    W4 w;
    const __bf16* p = wt + wofs + colb * 128 + quad * 8;
#pragma unroll
    for (int ks = 0; ks < 4; ++ks) w.b[ks] = *(const bf16x8*)(p + ks * 32);
    return w;
  };
  auto loadW256 = [&](int wofs) {
    W8 w;
    const __bf16* p = wt + wofs + colb * 256 + quad * 8;
#pragma unroll
    for (int ks = 0; ks < 8; ++ks) w.b[ks] = *(const bf16x8*)(p + ks * 32);
    return w;
  };
  auto loadW256half = [&](int wofs, int kh) {
    W4 w;
    const __bf16* p = wt + wofs + colb * 256 + kh * 128 + quad * 8;
#pragma unroll
    for (int ks = 0; ks < 4; ++ks) w.b[ks] = *(const bf16x8*)(p + ks * 32);
    return w;
  };

  auto gemmP = [&](floatx4 (&acc)[6], const W4& w, const __hip_bfloat16* in) {
    const __bf16* ab = (const __bf16*)(const void*)in;
#pragma unroll
    for (int ks = 0; ks < 4; ++ks) {
      int kk = ks * 32 + quad * 8;
#pragma unroll
      for (int mt = 0; mt < 6; ++mt) {
        bf16x8 a = *(const bf16x8*)(ab + (mt * 16 + nl) * LDW + kk);
        acc[mt] = __builtin_amdgcn_mfma_f32_16x16x32_bf16(a, w.b[ks], acc[mt], 0, 0, 0);
      }
    }
  };
  // shared-A dual gemm (one ds_read feeds two accumulators)
  auto gemmP2 = [&](floatx4 (&accA)[6], const W4& wA, floatx4 (&accB)[6],
                    const W4& wB, const __hip_bfloat16* in) {
    const __bf16* ab = (const __bf16*)(const void*)in;
#pragma unroll
    for (int ks = 0; ks < 4; ++ks) {
      int kk = ks * 32 + quad * 8;
#pragma unroll
      for (int mt = 0; mt < 6; ++mt) {
        bf16x8 a = *(const bf16x8*)(ab + (mt * 16 + nl) * LDW + kk);
        accA[mt] = __builtin_amdgcn_mfma_f32_16x16x32_bf16(a, wA.b[ks], accA[mt], 0, 0, 0);
        accB[mt] = __builtin_amdgcn_mfma_f32_16x16x32_bf16(a, wB.b[ks], accB[mt], 0, 0, 0);
      }
    }
  };
  auto gemm256P = [&](floatx4 (&acc)[6], const W8& w, const __hip_bfloat16* in) {
    int rofs0[6], rofs1[6];
#pragma unroll
    for (int mt = 0; mt < 6; ++mt) {
      int r = mt * 16 + nl;
      rofs1[mt] = r * LDW;
      int e = r % 6;
      rofs0[mt] = (r + ((e == 5) ? -5 : 1)) * LDW;
    }
    const __bf16* ab = (const __bf16*)(const void*)in;
#pragma unroll
    for (int ks = 0; ks < 8; ++ks) {
      int kk = (ks & 3) * 32 + quad * 8;
      const int* rofs = (ks < 4) ? rofs0 : rofs1;
#pragma unroll
      for (int mt = 0; mt < 6; ++mt) {
        bf16x8 a = *(const bf16x8*)(ab + rofs[mt] + kk);
        acc[mt] = __builtin_amdgcn_mfma_f32_16x16x32_bf16(a, w.b[ks], acc[mt], 0, 0, 0);
      }
    }
  };
  auto gemm32 = [&](floatx4 (&acc)[6], int wofs) {
    const __bf16* pb = (const __bf16*)(const void*)pxb;
    bf16x8 b0 = *(const bf16x8*)(wt + wofs + colb * 32 + quad * 8);
#pragma unroll
    for (int mt = 0; mt < 6; ++mt) {
      bf16x8 a = *(const bf16x8*)(pb + (mt * 16 + nl) * PXW + quad * 8);
      acc[mt] = __builtin_amdgcn_mfma_f32_16x16x32_bf16(a, b0, acc[mt], 0, 0, 0);
    }
  };
  auto store_act = [&](floatx4 (&acc)[6], int act, __hip_bfloat16* ob) {
#pragma unroll
    for (int mt = 0; mt < 6; ++mt)
#pragma unroll
      for (int r = 0; r < 4; ++r) {
        float z = acc[mt][r];
        if (act == 1) z = (z > 0.f) ? z : (__expf(z) - 1.f);
        else z = fmaxf(z, 0.f);
        ob[(mt * 16 + quad * 4 + r) * LDW + colb] = __float2bfloat16(z);
      }
  };

  floatx4 acc[6], acc2[6];

  // s1: hh = ELU(x @ e1w1 + b)  [K32]; prefetch e1w2
  initb(acc, 0); gemm32(acc, O_E1W1P);
  W4 w2 = loadW128(O_E1W2);
  store_act(acc, 1, bufA);
  __syncthreads();
  // s2: h = ELU(. @ e1w2 + b); prefetch e2w1 (K256)
  initb(acc, 1); gemmP(acc, w2, bufA);
  W8 w3 = loadW256(O_E2W1);
  store_act(acc, 1, bufB);
  __syncthreads();
  // s3: ELU([h_recv|h] @ e2w1 + b); prefetch e2w2
  initb(acc, 2); gemm256P(acc, w3, bufB);
  W4 w4 = loadW128(O_E2W2);
  store_act(acc, 1, bufA);
  __syncthreads();
  // s4: he = ELU(. @ e2w2 + b) -> bufB; prefetch e3w1 + e4w1[128:]
  initb(acc, 3); gemmP(acc, w4, bufA);
  W4 w5 = loadW128(O_E3W1);
  W4 w5b = loadW256half(O_E4W1, 1);
  store_act(acc, 1, bufB);
  __syncthreads();
  // s5: t1 = ELU(he @ e3w1 + b) -> bufA; acc2 = e4b1 + he @ e4w1[128:] (kept)
  initb(acc, 4); initb(acc2, 6);
  gemmP2(acc, w5, acc2, w5b, bufB);
  W4 w6 = loadW128(O_E3W2);
  store_act(acc, 1, bufA);
  __syncthreads();
  // s6: h2 = ELU(t1 @ e3w2 + b) -> bufB (he dead); prefetch e4w1[:128]
  initb(acc, 5); gemmP(acc, w6, bufA);
  W4 w7 = loadW256half(O_E4W1, 0);
  store_act(acc, 1, bufB);
  __syncthreads();
  // s7: h3h = ELU(acc2 + h2 @ e4w1[:128]) -> bufA; prefetch e4w2
  gemmP(acc2, w7, bufB);
  W4 w8 = loadW128(O_E4W2);
  store_act(acc2, 1, bufA);
  __syncthreads();
  // s8: h3 = ELU(. @ e4w2 + b) -> bufB
  initb(acc, 7); gemmP(acc, w8, bufA);
  store_act(acc, 1, bufB);
  __syncthreads();

  // s9: logits via N=16-padded MFMA tail (waves 0..5, one row-tile each)
  if (wave < 6) {
    int tile = wave;
    float bv = biasL[14 * 128 + nl];
    floatx4 lg = {bv, bv, bv, bv};
    const __bf16* ab = (const __bf16*)(const void*)bufB;
    const __bf16* wp = wt + O_EWOUT + nl * 128 + quad * 8;
#pragma unroll
    for (int ks = 0; ks < 4; ++ks) {
      bf16x8 a = *(const bf16x8*)(ab + (tile * 16 + nl) * LDW + ks * 32 + quad * 8);
      bf16x8 b = *(const bf16x8*)(wp + ks * 32);
      lg = __builtin_amdgcn_mfma_f32_16x16x32_bf16(a, b, lg, 0, 0, 0);
    }
    if (nl < 2) {
#pragma unroll
      for (int r = 0; r < 4; ++r)
        rtw[(tile * 16 + quad * 4 + r) * 2 + nl] = lg[r];
    }
  }
  __syncthreads();

  // s10: softmax + m1 both types [K32]: t0->bufA, t1->bufB; prefetch dm2 weights
  if (tid < 96) {
    float l0 = rtw[tid * 2], l1 = rtw[tid * 2 + 1];
    float mx = fmaxf(l0, l1);
    float ea = __expf(l0 - mx), eb = __expf(l1 - mx);
    float inv = 1.f / (ea + eb);
    rtw[tid * 2] = ea * inv; rtw[tid * 2 + 1] = eb * inv;
  }
  initb(acc, 8);  gemm32(acc, O_M1T0P);  store_act(acc, 2, bufA);
  initb(acc2, 9); gemm32(acc2, O_M1T1P); store_act(acc2, 2, bufB);
  W4 wm0 = loadW128(O_DM2T0);
  W4 wm1 = loadW128(O_DM2T1);
  __syncthreads();

  // s11: msg = rt0*relu(m1t0 @ w2t0 + b) + rt1*relu(m1t1 @ w2t1 + b)
  initb(acc, 10);  gemmP(acc, wm0, bufA);
  initb(acc2, 11); gemmP(acc2, wm1, bufB);
#pragma unroll
  for (int mt = 0; mt < 6; ++mt)
#pragma unroll
    for (int r = 0; r < 4; ++r) {
      int row = mt * 16 + quad * 4 + r;
      float r0 = rtw[row * 2], r1 = rtw[row * 2 + 1];
      acc[mt][r] = r0 * fmaxf(acc[mt][r], 0.f) + r1 * fmaxf(acc2[mt][r], 0.f);
    }
  W4 wd1 = loadW128(O_DO1);
  __syncthreads();

  // s12: agg (edge e -> node (e+1)%6) -> bufA
#pragma unroll
  for (int mt = 0; mt < 6; ++mt)
#pragma unroll
    for (int r = 0; r < 4; ++r) {
      int row = mt * 16 + quad * 4 + r;
      int e = row % 6;
      int orow = row + ((e == 5) ? -5 : 1);
      bufA[orow * LDW + colb] = __float2bfloat16(acc[mt][r]);
    }
  __syncthreads();

  // s13: p1 = relu([x|agg] @ d_out_w1 + b) -> bufB; prefetch d_out_w2
  initb(acc, 12); gemmP(acc, wd1, bufA); gemm32(acc, O_DO1XP);
  W4 wd2 = loadW128(O_DO2);
  store_act(acc, 2, bufB);
  __syncthreads();
  // s14: p2 = relu(. @ d_out_w2 + b) -> bufA
  initb(acc, 13); gemmP(acc, wd2, bufB);
  store_act(acc, 2, bufA);
  __syncthreads();

  // s15: out = x + p2 @ d_out_w3 + b3 via N=16-padded MFMA tail (waves 0..5)
  if (wave < 6) {
    int tile = wave;
    float bv = biasL[15 * 128 + nl];
    floatx4 d = {bv, bv, bv, bv};
    const __bf16* ab = (const __bf16*)(const void*)bufA;
    const __bf16* wp = wt + O_DW3 + nl * 128 + quad * 8;
#pragma unroll
    for (int ks = 0; ks < 4; ++ks) {
      bf16x8 a = *(const bf16x8*)(ab + (tile * 16 + nl) * LDW + ks * 32 + quad * 8);
      bf16x8 b = *(const bf16x8*)(wp + ks * 32);
      d = __builtin_amdgcn_mfma_f32_16x16x32_bf16(a, b, d, 0, 0, 0);
    }
    if (nl < 3) {
#pragma unroll
      for (int r = 0; r < 4; ++r) {
        int row = tile * 16 + quad * 4 + r;
        obuf[row * 3 + nl] = xs[row * 3 + nl] + d[r];
      }
    }
  }
  __syncthreads();
  for (int i = tid; i < 288; i += 512) out[gx + i] = obuf[i];
}

extern "C" void kernel_launch(void* const* d_in, const int* in_sizes, int n_in,
                              void* d_out, int out_size, void* d_ws, size_t ws_size,
                              hipStream_t stream) {
  const float* x       = (const float*)d_in[0];
  const float* e1w1    = (const float*)d_in[3];
  const float* e1b1    = (const float*)d_in[4];
  const float* e1w2    = (const float*)d_in[5];
  const float* e1b2    = (const float*)d_in[6];
  const float* e2w1    = (const float*)d_in[7];
  const float* e2b1    = (const float*)d_in[8];
  const float* e2w2    = (const float*)d_in[9];
  const float* e2b2    = (const float*)d_in[10];
  const float* e3w1    = (const float*)d_in[11];
  const float* e3b1    = (const float*)d_in[12];
  const float* e3w2    = (const float*)d_in[13];
  const float* e3b2    = (const float*)d_in[14];
  const float* e4w1    = (const float*)d_in[15];
  const float* e4b1    = (const float*)d_in[16];
  const float* e4w2    = (const float*)d_in[17];
  const float* e4b2    = (const float*)d_in[18];
  const float* ew_out  = (const float*)d_in[19];
  const float* eb_out  = (const float*)d_in[20];
  const float* dmsg_w1 = (const float*)d_in[21];
  const float* dmsg_b1 = (const float*)d_in[22];
  const float* dmsg_w2 = (const float*)d_in[23];
  const float* dmsg_b2 = (const float*)d_in[24];
  const float* dout_w1 = (const float*)d_in[25];
  const float* dout_b1 = (const float*)d_in[26];
  const float* dout_w2 = (const float*)d_in[27];
  const float* dout_b2 = (const float*)d_in[28];
  const float* dout_w3 = (const float*)d_in[29];
  const float* dout_b3 = (const float*)d_in[30];

  prep_kernel<<<(WS_ELEMS + 255) / 256, 256, 0, stream>>>(
      e1w2, e2w1, e2w2, e3w1, e3w2, e4w1, e4w2, dmsg_w2, dout_w1, dout_w2,
      ew_out, dout_w3, e1w1, dmsg_w1, (__hip_bfloat16*)d_ws);

  nri_fused<<<32768 / 16, 512, 0, stream>>>(
      x, e1b1, e1b2, e2b1, e2b2, e3b1, e3b2, e4b1, e4b2, eb_out,
      dmsg_b1, dmsg_b2, dout_b1, dout_b2, dout_b3,
      (const __bf16*)d_ws, (float*)d_out);
}

// Round 11
// 267.027 us; speedup vs baseline: 1.2966x; 1.0003x over previous
//
#include <hip/hip_runtime.h>
#include <hip/hip_bf16.h>

typedef __bf16 bf16x8 __attribute__((ext_vector_type(8)));
typedef float floatx4 __attribute__((ext_vector_type(4)));

#define LDW 136  // activation row stride (17 chunks of 8; chunks 0..15 used, XOR-swizzled)
#define PXW 40   // pre_msg row stride (cols 0..2 recv-x, 3..5 self-x, rest pad)

// ws layout (bf16 element offsets). Big mats: Wt[n][k]. K32 pads: [128 n][32 k].
// N16 tails: [16 n][128 k].
#define O_E1W2  0
#define O_E2W1  16384
#define O_E2W2  49152
#define O_E3W1  65536
#define O_E3W2  81920
#define O_E4W1  98304
#define O_E4W2  131072
#define O_DM2T0 147456
#define O_DM2T1 163840
#define O_DO1   180224
#define O_DO2   196608
#define O_EWOUT 212992
#define O_DW3   215040
#define O_E1W1P 217088
#define O_M1T0P 221184
#define O_M1T1P 225280
#define O_DO1XP 229376
#define WS_ELEMS 233472

__global__ void prep_kernel(const float* e1w2, const float* e2w1, const float* e2w2,
    const float* e3w1, const float* e3w2, const float* e4w1, const float* e4w2,
    const float* dmsg2, const float* dout1, const float* dout2,
    const float* ew_out, const float* dout_w3, const float* e1w1,
    const float* dmsg_w1, __hip_bfloat16* ws) {
  int idx = blockIdx.x * 256 + threadIdx.x;
  if (idx >= WS_ELEMS) return;
  float v;
  if (idx < O_E2W1)      { int l = idx;           v = e1w2[(l & 127) * 128 + (l >> 7)]; }
  else if (idx < O_E2W2) { int l = idx - O_E2W1;  v = e2w1[(l & 255) * 128 + (l >> 8)]; }
  else if (idx < O_E3W1) { int l = idx - O_E2W2;  v = e2w2[(l & 127) * 128 + (l >> 7)]; }
  else if (idx < O_E3W2) { int l = idx - O_E3W1;  v = e3w1[(l & 127) * 128 + (l >> 7)]; }
  else if (idx < O_E4W1) { int l = idx - O_E3W2;  v = e3w2[(l & 127) * 128 + (l >> 7)]; }
  else if (idx < O_E4W2) { int l = idx - O_E4W1;  v = e4w1[(l & 255) * 128 + (l >> 8)]; }
  else if (idx < O_DM2T0){ int l = idx - O_E4W2;  v = e4w2[(l & 127) * 128 + (l >> 7)]; }
  else if (idx < O_DM2T1){ int l = idx - O_DM2T0; v = dmsg2[(l & 127) * 128 + (l >> 7)]; }
  else if (idx < O_DO1)  { int l = idx - O_DM2T1; v = dmsg2[16384 + (l & 127) * 128 + (l >> 7)]; }
  else if (idx < O_DO2)  { int l = idx - O_DO1;   v = dout1[384 + (l & 127) * 128 + (l >> 7)]; }
  else if (idx < O_EWOUT){ int l = idx - O_DO2;   v = dout2[(l & 127) * 128 + (l >> 7)]; }
  else if (idx < O_DW3)  { int l = idx - O_EWOUT; int n = l >> 7;
                           v = (n < 2) ? ew_out[(l & 127) * 2 + n] : 0.f; }
  else if (idx < O_E1W1P){ int l = idx - O_DW3;   int n = l >> 7;
                           v = (n < 3) ? dout_w3[(l & 127) * 3 + n] : 0.f; }
  else if (idx < O_M1T0P){ int l = idx - O_E1W1P; int n = l >> 5, c = l & 31;
                           v = (c >= 3 && c < 6) ? e1w1[(c - 3) * 128 + n] : 0.f; }
  else if (idx < O_M1T1P){ int l = idx - O_M1T0P; int n = l >> 5, c = l & 31;
                           v = (c < 6) ? dmsg_w1[c * 128 + n] : 0.f; }
  else if (idx < O_DO1XP){ int l = idx - O_M1T1P; int n = l >> 5, c = l & 31;
                           v = (c < 6) ? dmsg_w1[768 + c * 128 + n] : 0.f; }
  else                   { int l = idx - O_DO1XP; int n = l >> 5, c = l & 31;
                           v = (c >= 3 && c < 6) ? dout1[(c - 3) * 128 + n] : 0.f; }
  ws[idx] = __float2bfloat16(v);
}

struct W4 { bf16x8 b[4]; };
struct W8 { bf16x8 b[8]; };

// R10 structure + XOR bank swizzle on activation buffers:
//   elem(row,col) = row*LDW + ((col>>3) ^ ((row>>2)&3))*8 + (col&7)
// Store rows are mt*16+quad*4+r -> key == quad -> all 4 quads hit distinct banks
// (kills the structural 4-way ds_write_b16 conflict; reads keep same bank stats).
__global__ __launch_bounds__(512, 4) void nri_fused(
    const float* __restrict__ x,
    const float* __restrict__ e1b1, const float* __restrict__ e1b2,
    const float* __restrict__ e2b1, const float* __restrict__ e2b2,
    const float* __restrict__ e3b1, const float* __restrict__ e3b2,
    const float* __restrict__ e4b1, const float* __restrict__ e4b2,
    const float* __restrict__ eb_out,
    const float* __restrict__ dmsg_b1, const float* __restrict__ dmsg_b2,
    const float* __restrict__ dout_b1, const float* __restrict__ dout_b2,
    const float* __restrict__ dout_b3,
    const __bf16* __restrict__ wt, float* __restrict__ out)
{
  const int tid  = threadIdx.x;
  const int wave = tid >> 6;
  const int lane = tid & 63;
  const int nl   = lane & 15;
  const int quad = lane >> 4;
  const int colb = wave * 16 + nl;                    // this wave's output column
  const int qk8  = (quad ^ ((nl >> 2) & 3)) * 8;      // swizzled k-chunk for reads (rows mt*16+nl)
  const int scol = (((colb >> 3) ^ quad) << 3) + (colb & 7);  // swizzled col for stores
  const int gx   = blockIdx.x * 288;

  __shared__ __align__(16) __hip_bfloat16 bufA[96 * LDW];
  __shared__ __align__(16) __hip_bfloat16 bufB[96 * LDW];
  __shared__ __align__(16) __hip_bfloat16 pxb[96 * PXW];
  __shared__ __align__(16) float biasL[16 * 128];
  __shared__ float rtw[192];
  __shared__ float xs[288];
  __shared__ float obuf[288];

  // ---- stage 0 (grid-stride everywhere: R6 lesson) ----
  for (int i = tid; i < 288; i += 512) xs[i] = x[gx + i];
  for (int i = tid; i < 2048; i += 512) {
    int row = i >> 7, c = i & 127;
    float v;
    switch (row) {
      case 0: v = e1b1[c]; break;   case 1: v = e1b2[c]; break;
      case 2: v = e2b1[c]; break;   case 3: v = e2b2[c]; break;
      case 4: v = e3b1[c]; break;   case 5: v = e3b2[c]; break;
      case 6: v = e4b1[c]; break;   case 7: v = e4b2[c]; break;
      case 8: v = dmsg_b1[c]; break;  case 9: v = dmsg_b1[128 + c]; break;
      case 10: v = dmsg_b2[c]; break; case 11: v = dmsg_b2[128 + c]; break;
      case 12: v = dout_b1[c]; break; case 13: v = dout_b2[c]; break;
      case 14: v = (c < 2) ? eb_out[c] : 0.f; break;
      default: v = (c < 3) ? dout_b3[c] : 0.f; break;
    }
    biasL[i] = v;
  }
  for (int i = tid; i < 96 * 32; i += 512) {
    int row = i >> 5, c = i & 31;
    int e = row % 6;
    float v = 0.f;
    if (c < 3)      { int rr = row + ((e == 5) ? -5 : 1); v = x[gx + rr * 3 + c]; }
    else if (c < 6) v = x[gx + row * 3 + (c - 3)];
    pxb[row * PXW + c] = __float2bfloat16(v);
  }
  __syncthreads();

  auto initb = [&](floatx4 (&a)[6], int brow) {
    float bv = biasL[brow * 128 + colb];
    floatx4 v = {bv, bv, bv, bv};
#pragma unroll
    for (int mt = 0; mt < 6; ++mt) a[mt] = v;
  };

  // weight fragment prefetch (pure global loads, no LDS dependency)
  auto loadW128 = [&](int wofs) {
    W4 w;
    const __bf16* p = wt + wofs + colb * 128 + quad * 8;
#pragma unroll
    for (int ks = 0; ks < 4; ++ks) w.b[ks] = *(const bf16x8*)(p + ks * 32);
    return w;
  };
  auto loadW256 = [&](int wofs) {
    W8 w;
    const __bf16* p = wt + wofs + colb * 256 + quad * 8;
#pragma unroll
    for (int ks = 0; ks < 8; ++ks) w.b[ks] = *(const bf16x8*)(p + ks * 32);
    return w;
  };
  auto loadW256half = [&](int wofs, int kh) {
    W4 w;
    const __bf16* p = wt + wofs + colb * 256 + kh * 128 + quad * 8;
#pragma unroll
    for (int ks = 0; ks < 4; ++ks) w.b[ks] = *(const bf16x8*)(p + ks * 32);
    return w;
  };

  auto gemmP = [&](floatx4 (&acc)[6], const W4& w, const __hip_bfloat16* in) {
    const __bf16* ab = (const __bf16*)(const void*)in;
#pragma unroll
    for (int ks = 0; ks < 4; ++ks) {
      int kk = ks * 32 + qk8;
#pragma unroll
      for (int mt = 0; mt < 6; ++mt) {
        bf16x8 a = *(const bf16x8*)(ab + (mt * 16 + nl) * LDW + kk);
        acc[mt] = __builtin_amdgcn_mfma_f32_16x16x32_bf16(a, w.b[ks], acc[mt], 0, 0, 0);
      }
    }
  };
  // shared-A dual gemm (one ds_read feeds two accumulators)
  auto gemmP2 = [&](floatx4 (&accA)[6], const W4& wA, floatx4 (&accB)[6],
                    const W4& wB, const __hip_bfloat16* in) {
    const __bf16* ab = (const __bf16*)(const void*)in;
#pragma unroll
    for (int ks = 0; ks < 4; ++ks) {
      int kk = ks * 32 + qk8;
#pragma unroll
      for (int mt = 0; mt < 6; ++mt) {
        bf16x8 a = *(const bf16x8*)(ab + (mt * 16 + nl) * LDW + kk);
        accA[mt] = __builtin_amdgcn_mfma_f32_16x16x32_bf16(a, wA.b[ks], accA[mt], 0, 0, 0);
        accB[mt] = __builtin_amdgcn_mfma_f32_16x16x32_bf16(a, wB.b[ks], accB[mt], 0, 0, 0);
      }
    }
  };
  auto gemm256P = [&](floatx4 (&acc)[6], const W8& w, const __hip_bfloat16* in) {
    int rofs0[6], qk0[6], rofs1[6];
#pragma unroll
    for (int mt = 0; mt < 6; ++mt) {
      int r = mt * 16 + nl;
      rofs1[mt] = r * LDW;
      int e = r % 6;
      int r0 = r + ((e == 5) ? -5 : 1);
      rofs0[mt] = r0 * LDW;
      qk0[mt] = (quad ^ ((r0 >> 2) & 3)) * 8;   // swizzle key for remapped row
    }
    const __bf16* ab = (const __bf16*)(const void*)in;
#pragma unroll
    for (int ks = 0; ks < 8; ++ks) {
#pragma unroll
      for (int mt = 0; mt < 6; ++mt) {
        int kk = (ks & 3) * 32 + ((ks < 4) ? qk0[mt] : qk8);
        int ro = (ks < 4) ? rofs0[mt] : rofs1[mt];
        bf16x8 a = *(const bf16x8*)(ab + ro + kk);
        acc[mt] = __builtin_amdgcn_mfma_f32_16x16x32_bf16(a, w.b[ks], acc[mt], 0, 0, 0);
      }
    }
  };
  auto gemm32 = [&](floatx4 (&acc)[6], int wofs) {
    const __bf16* pb = (const __bf16*)(const void*)pxb;
    bf16x8 b0 = *(const bf16x8*)(wt + wofs + colb * 32 + quad * 8);
#pragma unroll
    for (int mt = 0; mt < 6; ++mt) {
      bf16x8 a = *(const bf16x8*)(pb + (mt * 16 + nl) * PXW + quad * 8);
      acc[mt] = __builtin_amdgcn_mfma_f32_16x16x32_bf16(a, b0, acc[mt], 0, 0, 0);
    }
  };
  auto store_act = [&](floatx4 (&acc)[6], int act, __hip_bfloat16* ob) {
#pragma unroll
    for (int mt = 0; mt < 6; ++mt)
#pragma unroll
      for (int r = 0; r < 4; ++r) {
        float z = acc[mt][r];
        if (act == 1) z = (z > 0.f) ? z : (__expf(z) - 1.f);
        else z = fmaxf(z, 0.f);
        ob[(mt * 16 + quad * 4 + r) * LDW + scol] = __float2bfloat16(z);
      }
  };

  floatx4 acc[6], acc2[6];

  // s1: hh = ELU(x @ e1w1 + b)  [K32]; prefetch e1w2
  initb(acc, 0); gemm32(acc, O_E1W1P);
  W4 w2 = loadW128(O_E1W2);
  store_act(acc, 1, bufA);
  __syncthreads();
  // s2: h = ELU(. @ e1w2 + b); prefetch e2w1 (K256)
  initb(acc, 1); gemmP(acc, w2, bufA);
  W8 w3 = loadW256(O_E2W1);
  store_act(acc, 1, bufB);
  __syncthreads();
  // s3: ELU([h_recv|h] @ e2w1 + b); prefetch e2w2
  initb(acc, 2); gemm256P(acc, w3, bufB);
  W4 w4 = loadW128(O_E2W2);
  store_act(acc, 1, bufA);
  __syncthreads();
  // s4: he = ELU(. @ e2w2 + b) -> bufB; prefetch e3w1 + e4w1[128:]
  initb(acc, 3); gemmP(acc, w4, bufA);
  W4 w5 = loadW128(O_E3W1);
  W4 w5b = loadW256half(O_E4W1, 1);
  store_act(acc, 1, bufB);
  __syncthreads();
  // s5: t1 = ELU(he @ e3w1 + b) -> bufA; acc2 = e4b1 + he @ e4w1[128:] (kept)
  initb(acc, 4); initb(acc2, 6);
  gemmP2(acc, w5, acc2, w5b, bufB);
  W4 w6 = loadW128(O_E3W2);
  store_act(acc, 1, bufA);
  __syncthreads();
  // s6: h2 = ELU(t1 @ e3w2 + b) -> bufB (he dead); prefetch e4w1[:128]
  initb(acc, 5); gemmP(acc, w6, bufA);
  W4 w7 = loadW256half(O_E4W1, 0);
  store_act(acc, 1, bufB);
  __syncthreads();
  // s7: h3h = ELU(acc2 + h2 @ e4w1[:128]) -> bufA; prefetch e4w2
  gemmP(acc2, w7, bufB);
  W4 w8 = loadW128(O_E4W2);
  store_act(acc2, 1, bufA);
  __syncthreads();
  // s8: h3 = ELU(. @ e4w2 + b) -> bufB
  initb(acc, 7); gemmP(acc, w8, bufA);
  store_act(acc, 1, bufB);
  __syncthreads();

  // s9: logits via N=16-padded MFMA tail (waves 0..5, one row-tile each)
  if (wave < 6) {
    int tile = wave;
    float bv = biasL[14 * 128 + nl];
    floatx4 lg = {bv, bv, bv, bv};
    const __bf16* ab = (const __bf16*)(const void*)bufB;
    const __bf16* wp = wt + O_EWOUT + nl * 128 + quad * 8;
#pragma unroll
    for (int ks = 0; ks < 4; ++ks) {
      bf16x8 a = *(const bf16x8*)(ab + (tile * 16 + nl) * LDW + ks * 32 + qk8);
      bf16x8 b = *(const bf16x8*)(wp + ks * 32);
      lg = __builtin_amdgcn_mfma_f32_16x16x32_bf16(a, b, lg, 0, 0, 0);
    }
    if (nl < 2) {
#pragma unroll
      for (int r = 0; r < 4; ++r)
        rtw[(tile * 16 + quad * 4 + r) * 2 + nl] = lg[r];
    }
  }
  __syncthreads();

  // s10: softmax + m1 both types [K32]: t0->bufA, t1->bufB; prefetch dm2 weights
  if (tid < 96) {
    float l0 = rtw[tid * 2], l1 = rtw[tid * 2 + 1];
    float mx = fmaxf(l0, l1);
    float ea = __expf(l0 - mx), eb = __expf(l1 - mx);
    float inv = 1.f / (ea + eb);
    rtw[tid * 2] = ea * inv; rtw[tid * 2 + 1] = eb * inv;
  }
  initb(acc, 8);  gemm32(acc, O_M1T0P);  store_act(acc, 2, bufA);
  initb(acc2, 9); gemm32(acc2, O_M1T1P); store_act(acc2, 2, bufB);
  W4 wm0 = loadW128(O_DM2T0);
  W4 wm1 = loadW128(O_DM2T1);
  __syncthreads();

  // s11: msg = rt0*relu(m1t0 @ w2t0 + b) + rt1*relu(m1t1 @ w2t1 + b)
  initb(acc, 10);  gemmP(acc, wm0, bufA);
  initb(acc2, 11); gemmP(acc2, wm1, bufB);
#pragma unroll
  for (int mt = 0; mt < 6; ++mt)
#pragma unroll
    for (int r = 0; r < 4; ++r) {
      int row = mt * 16 + quad * 4 + r;
      float r0 = rtw[row * 2], r1 = rtw[row * 2 + 1];
      acc[mt][r] = r0 * fmaxf(acc[mt][r], 0.f) + r1 * fmaxf(acc2[mt][r], 0.f);
    }
  W4 wd1 = loadW128(O_DO1);
  __syncthreads();

  // s12: agg (edge e -> node (e+1)%6) -> bufA (swizzle key from orow)
#pragma unroll
  for (int mt = 0; mt < 6; ++mt)
#pragma unroll
    for (int r = 0; r < 4; ++r) {
      int row = mt * 16 + quad * 4 + r;
      int e = row % 6;
      int orow = row + ((e == 5) ? -5 : 1);
      int oc = (((colb >> 3) ^ ((orow >> 2) & 3)) << 3) + (colb & 7);
      bufA[orow * LDW + oc] = __float2bfloat16(acc[mt][r]);
    }
  __syncthreads();

  // s13: p1 = relu([x|agg] @ d_out_w1 + b) -> bufB; prefetch d_out_w2
  initb(acc, 12); gemmP(acc, wd1, bufA); gemm32(acc, O_DO1XP);
  W4 wd2 = loadW128(O_DO2);
  store_act(acc, 2, bufB);
  __syncthreads();
  // s14: p2 = relu(. @ d_out_w2 + b) -> bufA
  initb(acc, 13); gemmP(acc, wd2, bufB);
  store_act(acc, 2, bufA);
  __syncthreads();

  // s15: out = x + p2 @ d_out_w3 + b3 via N=16-padded MFMA tail (waves 0..5)
  if (wave < 6) {
    int tile = wave;
    float bv = biasL[15 * 128 + nl];
    floatx4 d = {bv, bv, bv, bv};
    const __bf16* ab = (const __bf16*)(const void*)bufA;
    const __bf16* wp = wt + O_DW3 + nl * 128 + quad * 8;
#pragma unroll
    for (int ks = 0; ks < 4; ++ks) {
      bf16x8 a = *(const bf16x8*)(ab + (tile * 16 + nl) * LDW + ks * 32 + qk8);
      bf16x8 b = *(const bf16x8*)(wp + ks * 32);
      d = __builtin_amdgcn_mfma_f32_16x16x32_bf16(a, b, d, 0, 0, 0);
    }
    if (nl < 3) {
#pragma unroll
      for (int r = 0; r < 4; ++r) {
        int row = tile * 16 + quad * 4 + r;
        obuf[row * 3 + nl] = xs[row * 3 + nl] + d[r];
      }
    }
  }
  __syncthreads();
  for (int i = tid; i < 288; i += 512) out[gx + i] = obuf[i];
}

extern "C" void kernel_launch(void* const* d_in, const int* in_sizes, int n_in,
                              void* d_out, int out_size, void* d_ws, size_t ws_size,
                              hipStream_t stream) {
  const float* x       = (const float*)d_in[0];
  const float* e1w1    = (const float*)d_in[3];
  const float* e1b1    = (const float*)d_in[4];
  const float* e1w2    = (const float*)d_in[5];
  const float* e1b2    = (const float*)d_in[6];
  const float* e2w1    = (const float*)d_in[7];
  const float* e2b1    = (const float*)d_in[8];
  const float* e2w2    = (const float*)d_in[9];
  const float* e2b2    = (const float*)d_in[10];
  const float* e3w1    = (const float*)d_in[11];
  const float* e3b1    = (const float*)d_in[12];
  const float* e3w2    = (const float*)d_in[13];
  const float* e3b2    = (const float*)d_in[14];
  const float* e4w1    = (const float*)d_in[15];
  const float* e4b1    = (const float*)d_in[16];
  const float* e4w2    = (const float*)d_in[17];
  const float* e4b2    = (const float*)d_in[18];
  const float* ew_out  = (const float*)d_in[19];
  const float* eb_out  = (const float*)d_in[20];
  const float* dmsg_w1 = (const float*)d_in[21];
  const float* dmsg_b1 = (const float*)d_in[22];
  const float* dmsg_w2 = (const float*)d_in[23];
  const float* dmsg_b2 = (const float*)d_in[24];
  const float* dout_w1 = (const float*)d_in[25];
  const float* dout_b1 = (const float*)d_in[26];
  const float* dout_w2 = (const float*)d_in[27];
  const float* dout_b2 = (const float*)d_in[28];
  const float* dout_w3 = (const float*)d_in[29];
  const float* dout_b3 = (const float*)d_in[30];

  prep_kernel<<<(WS_ELEMS + 255) / 256, 256, 0, stream>>>(
      e1w2, e2w1, e2w2, e3w1, e3w2, e4w1, e4w2, dmsg_w2, dout_w1, dout_w2,
      ew_out, dout_w3, e1w1, dmsg_w1, (__hip_bfloat16*)d_ws);

  nri_fused<<<32768 / 16, 512, 0, stream>>>(
      x, e1b1, e1b2, e2b1, e2b2, e3b1, e3b2, e4b1, e4b2, eb_out,
      dmsg_b1, dmsg_b2, dout_b1, dout_b2, dout_b3,
      (const __bf16*)d_ws, (float*)d_out);
}